// Round 1
// baseline (756.778 us; speedup 1.0000x reference)
//
#include <hip/hip_runtime.h>

// SO3Conv: psi = einsum('ni,xyn->xyi', D, w)/sqrt(512); then per-l block-diag
// channel mixing. Restructured as per-degree GEMMs:
//   Y_l[(b,i),(yo,v)] = A_l[(b,i),(x,u)] . P_l[(x,u),(yo,v)]
// with P_l = scaled/permuted psi, A_l = permuted x.
// LMAX=5, d_l=2l+1, off_l = {0,1,10,35,84,165}, S=286, F=128, B=512, NG=512.

#define NTHREADS 256

// ---------------------------------------------------------------------------
// Kernel 1: psi GEMM.  C[m=(x*128+y)][s] = sum_g w[m*512+g] * D[g*286+s]
// Epilogue scatters scaled result into P_l[(x*d+u)*(128d) + y*d+v],
// P_l base offset = 16384*off_l floats.  scale = 1/(256*sqrt(d)).
// M=16384, N=286, K=512.  Tile 64x64, Ktile 16, 4x4 per thread.
// ---------------------------------------------------------------------------
__global__ __launch_bounds__(NTHREADS)
void psi_gemm(const float* __restrict__ w, const float* __restrict__ Dm,
              float* __restrict__ P) {
  __shared__ float As[16][64];
  __shared__ float Bs[16][64];
  const int tid = threadIdx.x;
  const int tx = tid & 15, ty = tid >> 4;
  const int m0 = blockIdx.x * 64;
  const int n0 = blockIdx.y * 64;
  float acc[4][4] = {};
  const int mlA = tid >> 2, k4A = (tid & 3) << 2;
  const int klB = tid >> 4, n4B = (tid & 15) << 2;
  for (int kt = 0; kt < 512; kt += 16) {
    float4 av = *reinterpret_cast<const float4*>(&w[(m0 + mlA) * 512 + kt + k4A]);
    As[k4A + 0][mlA] = av.x;
    As[k4A + 1][mlA] = av.y;
    As[k4A + 2][mlA] = av.z;
    As[k4A + 3][mlA] = av.w;
#pragma unroll
    for (int j = 0; j < 4; ++j) {
      const int n = n0 + n4B + j;
      Bs[klB][n4B + j] = (n < 286) ? Dm[(kt + klB) * 286 + n] : 0.0f;
    }
    __syncthreads();
#pragma unroll
    for (int k = 0; k < 16; ++k) {
      float a[4], b[4];
      *reinterpret_cast<float4*>(&a[0]) = *reinterpret_cast<const float4*>(&As[k][ty * 4]);
      *reinterpret_cast<float4*>(&b[0]) = *reinterpret_cast<const float4*>(&Bs[k][tx * 4]);
#pragma unroll
      for (int r = 0; r < 4; ++r)
#pragma unroll
        for (int c = 0; c < 4; ++c)
          acc[r][c] = fmaf(a[r], b[c], acc[r][c]);
    }
    __syncthreads();
  }
  // Scatter epilogue: (m=(x,y), s=(off,u,v)) -> P_l[(x*d+u)][(y*d+v)]
#pragma unroll
  for (int c = 0; c < 4; ++c) {
    const int s = n0 + tx * 4 + c;
    if (s >= 286) continue;
    int off, d;
    if (s >= 165)      { off = 165; d = 11; }
    else if (s >= 84)  { off = 84;  d = 9; }
    else if (s >= 35)  { off = 35;  d = 7; }
    else if (s >= 10)  { off = 10;  d = 5; }
    else if (s >= 1)   { off = 1;   d = 3; }
    else               { off = 0;   d = 1; }
    const int rel = s - off;
    const int u = rel / d, v = rel - u * d;
    const float scale = 1.0f / (256.0f * sqrtf((float)d));
    float* Pl = P + off * 16384;
    const int N = 128 * d;
#pragma unroll
    for (int r = 0; r < 4; ++r) {
      const int m = m0 + ty * 4 + r;
      const int x = m >> 7, y = m & 127;
      Pl[(x * d + u) * N + (y * d + v)] = acc[r][c] * scale;
    }
  }
}

// ---------------------------------------------------------------------------
// Kernel 2: build A_l[(b*d+i)*(128d) + x*d+u] = X[(b*128+x)*286 + off + u*d + i]
// A_l base offset = 65536*off_l floats. Dest-indexed (coalesced writes).
// Total elements = 65536*286 = 18,743,296.
// ---------------------------------------------------------------------------
__global__ __launch_bounds__(NTHREADS)
void build_A(const float* __restrict__ X, float* __restrict__ A) {
  const int idx = blockIdx.x * NTHREADS + threadIdx.x;
  int off, d;
  if (idx >= 65536 * 165)      { off = 165; d = 11; }
  else if (idx >= 65536 * 84)  { off = 84;  d = 9; }
  else if (idx >= 65536 * 35)  { off = 35;  d = 7; }
  else if (idx >= 65536 * 10)  { off = 10;  d = 5; }
  else if (idx >= 65536 * 1)   { off = 1;   d = 3; }
  else                         { off = 0;   d = 1; }
  const int rel = idx - 65536 * off;
  const int K = 128 * d;
  const int m = rel / K;
  const int k = rel - m * K;
  const int b = m / d, i = m - b * d;
  const int x = k / d, u = k - x * d;
  A[idx] = X[(b * 128 + x) * 286 + off + u * d + i];
}

// ---------------------------------------------------------------------------
// Kernel 3: fused per-degree GEMMs. One launch, 1144 blocks:
//   l=0: blocks [0,4)    grid 4x1   (M=512,  N=K=128)
//   l=1: [4,40)    12x3 ; l=2: [40,140)  20x5 ; l=3: [140,336) 28x7
//   l=4: [336,660) 36x9 ; l=5: [660,1144) 44x11
// Tile 128x128, Ktile 16, 8x8 per thread. Epilogue scatters into out.
// ---------------------------------------------------------------------------
__global__ __launch_bounds__(NTHREADS)
void main_gemm(const float* __restrict__ Aall, const float* __restrict__ Pall,
               float* __restrict__ out) {
  int bx = blockIdx.x;
  int off, d;
  if (bx >= 660)      { off = 165; d = 11; bx -= 660; }
  else if (bx >= 336) { off = 84;  d = 9;  bx -= 336; }
  else if (bx >= 140) { off = 35;  d = 7;  bx -= 140; }
  else if (bx >= 40)  { off = 10;  d = 5;  bx -= 40; }
  else if (bx >= 4)   { off = 1;   d = 3;  bx -= 4; }
  else                { off = 0;   d = 1; }
  const int bm = bx % (4 * d);
  const int bn = bx / (4 * d);
  const int Kn = 128 * d, Nn = 128 * d;
  const float* A  = Aall + (long long)65536 * off;
  const float* Bm = Pall + (long long)16384 * off;
  const int m0 = bm * 128, n0 = bn * 128;

  __shared__ float As[16][128];
  __shared__ float Bs[16][128];
  const int tid = threadIdx.x;
  const int tx = tid & 15, ty = tid >> 4;
  float acc[8][8] = {};

  for (int kt = 0; kt < Kn; kt += 16) {
#pragma unroll
    for (int q = 0; q < 2; ++q) {
      const int vec = tid * 2 + q;
      const int ml = vec >> 2, k4 = (vec & 3) << 2;
      float4 av = *reinterpret_cast<const float4*>(&A[(m0 + ml) * Kn + kt + k4]);
      As[k4 + 0][ml] = av.x;
      As[k4 + 1][ml] = av.y;
      As[k4 + 2][ml] = av.z;
      As[k4 + 3][ml] = av.w;
      const int kl = vec >> 5, n4 = (vec & 31) << 2;
      float4 bv = *reinterpret_cast<const float4*>(&Bm[(kt + kl) * Nn + n0 + n4]);
      *reinterpret_cast<float4*>(&Bs[kl][n4]) = bv;
    }
    __syncthreads();
#pragma unroll
    for (int k = 0; k < 16; ++k) {
      float a[8], b[8];
      *reinterpret_cast<float4*>(&a[0]) = *reinterpret_cast<const float4*>(&As[k][ty * 8]);
      *reinterpret_cast<float4*>(&a[4]) = *reinterpret_cast<const float4*>(&As[k][ty * 8 + 4]);
      *reinterpret_cast<float4*>(&b[0]) = *reinterpret_cast<const float4*>(&Bs[k][tx * 8]);
      *reinterpret_cast<float4*>(&b[4]) = *reinterpret_cast<const float4*>(&Bs[k][tx * 8 + 4]);
#pragma unroll
      for (int r = 0; r < 8; ++r)
#pragma unroll
        for (int c = 0; c < 8; ++c)
          acc[r][c] = fmaf(a[r], b[c], acc[r][c]);
    }
    __syncthreads();
  }

  // Scatter epilogue: row m=(b,i), col n=(yo,v) -> out[b][yo][off + v*d + i]
#pragma unroll
  for (int r = 0; r < 8; ++r) {
    const int m = m0 + ty * 8 + r;
    const int bb = m / d, i = m - bb * d;
    float* orow = out + (long long)bb * (128 * 286) + off + i;
#pragma unroll
    for (int c = 0; c < 8; ++c) {
      const int n = n0 + tx * 8 + c;
      const int yo = n / d, v = n - yo * d;
      orow[yo * 286 + v * d] = acc[r][c];
    }
  }
}

// ---------------------------------------------------------------------------
extern "C" void kernel_launch(void* const* d_in, const int* in_sizes, int n_in,
                              void* d_out, int out_size, void* d_ws, size_t ws_size,
                              hipStream_t stream) {
  const float* x  = (const float*)d_in[0];  // (512,128,286)
  const float* w  = (const float*)d_in[1];  // (128,128,512)
  const float* Dm = (const float*)d_in[2];  // (512,286)
  float* out = (float*)d_out;               // (512,128,286)

  // Workspace layout (floats):
  //   P: 16384*286 = 4,687,872   (per-l P_l at offset 16384*off_l)
  //   A: 65536*286 = 18,743,296  (per-l A_l at offset 65536*off_l)
  float* P = (float*)d_ws;
  float* A = P + 4687872;

  psi_gemm<<<dim3(256, 5), dim3(NTHREADS), 0, stream>>>(w, Dm, P);
  build_A<<<dim3(73216), dim3(NTHREADS), 0, stream>>>(x, A);
  main_gemm<<<dim3(1144), dim3(NTHREADS), 0, stream>>>(A, P, out);
}

// Round 2
// 295.733 us; speedup vs baseline: 2.5590x; 2.5590x over previous
//
#include <hip/hip_runtime.h>
#include <hip/hip_bf16.h>

// SO3Conv restructured:
//   PT_l[(yo,v)][(x,u)] = psi_l scaled, bf16   (psi = D.w/sqrt(512))
//   A_l[(b,i)][(x,u)]   = permuted x, bf16
//   Y_l[(b,i)][(yo,v)]  = A_l . PT_l^T  via mfma_f32_16x16x32_bf16
// l=0..5, d=2l+1, off_l = {0,1,10,35,84,165} = sum of d'^2 below l.
// PT_l base = 16384*off_l elems; A_l base = 65536*off_l elems.

#define NT 256
typedef __bf16 bf16x8 __attribute__((ext_vector_type(8)));
typedef float f32x4 __attribute__((ext_vector_type(4)));
typedef unsigned int u32;

__device__ __forceinline__ void gload_lds16(const void* g, void* l) {
  __builtin_amdgcn_global_load_lds(
      (const __attribute__((address_space(1))) u32*)g,
      (__attribute__((address_space(3))) u32*)l, 16, 0, 0);
}

__device__ __forceinline__ void decode_s(int s, int& off, int& d) {
  if (s >= 165)      { off = 165; d = 11; }
  else if (s >= 84)  { off = 84;  d = 9; }
  else if (s >= 35)  { off = 35;  d = 7; }
  else if (s >= 10)  { off = 10;  d = 5; }
  else if (s >= 1)   { off = 1;   d = 3; }
  else               { off = 0;   d = 1; }
}

// ---------------------------------------------------------------------------
// Kernel 1: psi GEMM (f32 compute).  C[m=(x*128+y)][s] = sum_g w[m,g]*D[g,s]
// Epilogue: PT_l[(y*d+v)*(128d) + x*d+u] = bf16(C * 1/(256*sqrt(d))).
// M=16384, N=286, K=512. Tile 64x64, Kt=16, 4x4/thread.
// ---------------------------------------------------------------------------
__global__ __launch_bounds__(NT)
void psi_gemm(const float* __restrict__ w, const float* __restrict__ Dm,
              __hip_bfloat16* __restrict__ PT) {
  __shared__ float As[16][64];
  __shared__ float Bs[16][64];
  const int tid = threadIdx.x;
  const int tx = tid & 15, ty = tid >> 4;
  const int m0 = blockIdx.x * 64;
  const int n0 = blockIdx.y * 64;
  float acc[4][4] = {};
  const int mlA = tid >> 2, k4A = (tid & 3) << 2;
  const int klB = tid >> 4, n4B = (tid & 15) << 2;
  for (int kt = 0; kt < 512; kt += 16) {
    float4 av = *reinterpret_cast<const float4*>(&w[(m0 + mlA) * 512 + kt + k4A]);
    As[k4A + 0][mlA] = av.x;
    As[k4A + 1][mlA] = av.y;
    As[k4A + 2][mlA] = av.z;
    As[k4A + 3][mlA] = av.w;
#pragma unroll
    for (int j = 0; j < 4; ++j) {
      const int n = n0 + n4B + j;
      Bs[klB][n4B + j] = (n < 286) ? Dm[(kt + klB) * 286 + n] : 0.0f;
    }
    __syncthreads();
#pragma unroll
    for (int k = 0; k < 16; ++k) {
      float a[4], b[4];
      *reinterpret_cast<float4*>(&a[0]) = *reinterpret_cast<const float4*>(&As[k][ty * 4]);
      *reinterpret_cast<float4*>(&b[0]) = *reinterpret_cast<const float4*>(&Bs[k][tx * 4]);
#pragma unroll
      for (int r = 0; r < 4; ++r)
#pragma unroll
        for (int c = 0; c < 4; ++c)
          acc[r][c] = fmaf(a[r], b[c], acc[r][c]);
    }
    __syncthreads();
  }
#pragma unroll
  for (int c = 0; c < 4; ++c) {
    const int s = n0 + tx * 4 + c;
    if (s >= 286) continue;
    int off, d;
    decode_s(s, off, d);
    const int rel = s - off;
    const int u = rel / d, v = rel - u * d;
    const float scale = 1.0f / (256.0f * sqrtf((float)d));
    __hip_bfloat16* Pl = PT + off * 16384;
    const int Kd = 128 * d;
#pragma unroll
    for (int r = 0; r < 4; ++r) {
      const int m = m0 + ty * 4 + r;
      const int x = m >> 7, y = m & 127;
      Pl[(y * d + v) * Kd + (x * d + u)] = __float2bfloat16(acc[r][c] * scale);
    }
  }
}

// ---------------------------------------------------------------------------
// Kernel 2: A_l[(b*d+i)*(128d) + x*d+u] = bf16( X[(b*128+x)*286 + off+u*d+i] )
// ---------------------------------------------------------------------------
__global__ __launch_bounds__(NT)
void build_A(const float* __restrict__ X, __hip_bfloat16* __restrict__ A) {
  const int idx = blockIdx.x * NT + threadIdx.x;
  int off, d;
  if (idx >= 65536 * 165)      { off = 165; d = 11; }
  else if (idx >= 65536 * 84)  { off = 84;  d = 9; }
  else if (idx >= 65536 * 35)  { off = 35;  d = 7; }
  else if (idx >= 65536 * 10)  { off = 10;  d = 5; }
  else if (idx >= 65536 * 1)   { off = 1;   d = 3; }
  else                         { off = 0;   d = 1; }
  const int rel = idx - 65536 * off;
  const int K = 128 * d;
  const int m = rel / K;
  const int k = rel - m * K;
  const int b = m / d, i = m - b * d;
  const int x = k / d, u = k - x * d;
  A[idx] = __float2bfloat16(X[(b * 128 + x) * 286 + off + u * d + i]);
}

// ---------------------------------------------------------------------------
// Kernel 3: MFMA main GEMM. 1144 blocks, 128x128 tiles, BK=64, 4 waves (2x2),
// each wave 64x64 out = 4x4 frags of 16x16, mfma_f32_16x16x32_bf16.
// LDS: sA[128][64], sB[128][64] bf16, XOR-swizzled 16B slots (slot ^= row&7),
// staged via global_load_lds w/ pre-swizzled per-lane global source (linear dest).
// Epilogue scatters f32 into out[b][yo][off + v*d + i].
// ---------------------------------------------------------------------------
__global__ __launch_bounds__(NT)
void main_gemm(const __hip_bfloat16* __restrict__ Aall,
               const __hip_bfloat16* __restrict__ PTall,
               float* __restrict__ out) {
  int bx = blockIdx.x;
  int off, d;
  if (bx >= 660)      { off = 165; d = 11; bx -= 660; }
  else if (bx >= 336) { off = 84;  d = 9;  bx -= 336; }
  else if (bx >= 140) { off = 35;  d = 7;  bx -= 140; }
  else if (bx >= 40)  { off = 10;  d = 5;  bx -= 40; }
  else if (bx >= 4)   { off = 1;   d = 3;  bx -= 4; }
  else                { off = 0;   d = 1; }
  const int bm = bx % (4 * d);
  const int bn = bx / (4 * d);
  const int Kn = 128 * d;
  const __hip_bfloat16* A  = Aall  + 65536 * off;
  const __hip_bfloat16* BT = PTall + 16384 * off;
  const int m0 = bm * 128, n0 = bn * 128;

  __shared__ __hip_bfloat16 sA[128 * 64];
  __shared__ __hip_bfloat16 sB[128 * 64];

  const int tid = threadIdx.x;
  const int lane = tid & 63, wave = tid >> 6;
  const int wr = wave & 1, wc = wave >> 1;      // wave -> 64x64 quadrant
  const int r15 = lane & 15, khi = lane >> 4;   // fragment lane decomposition

  f32x4 acc[4][4] = {};

  // Per-thread staging geometry (4 chunks of 16B each for A and B):
  //   q = c*256 + tid ; row = q>>3 ; slot = q&7 ; src col chunk = slot ^ (row&7)
  for (int kt = 0; kt < Kn; kt += 64) {
#pragma unroll
    for (int c = 0; c < 4; ++c) {
      const int q = c * 256 + tid;
      const int row = q >> 3, slot = q & 7;
      const int scol = ((slot ^ (row & 7)) << 3);
      gload_lds16(&A[(m0 + row) * Kn + kt + scol],
                  &sA[(c * 256 + wave * 64) << 3]);
      gload_lds16(&BT[(n0 + row) * Kn + kt + scol],
                  &sB[(c * 256 + wave * 64) << 3]);
    }
    __syncthreads();   // vmcnt(0) drain: staged tiles visible to all waves

    bf16x8 af[4][2], bf[4][2];
#pragma unroll
    for (int m = 0; m < 4; ++m)
#pragma unroll
      for (int kk = 0; kk < 2; ++kk) {
        const int row = wr * 64 + m * 16 + r15;
        const int slot = (kk * 4 + khi) ^ (row & 7);
        af[m][kk] = *reinterpret_cast<const bf16x8*>(&sA[row * 64 + slot * 8]);
      }
#pragma unroll
    for (int n = 0; n < 4; ++n)
#pragma unroll
      for (int kk = 0; kk < 2; ++kk) {
        const int row = wc * 64 + n * 16 + r15;
        const int slot = (kk * 4 + khi) ^ (row & 7);
        bf[n][kk] = *reinterpret_cast<const bf16x8*>(&sB[row * 64 + slot * 8]);
      }
#pragma unroll
    for (int kk = 0; kk < 2; ++kk)
#pragma unroll
      for (int m = 0; m < 4; ++m)
#pragma unroll
        for (int n = 0; n < 4; ++n)
          acc[m][n] = __builtin_amdgcn_mfma_f32_16x16x32_bf16(
              af[m][kk], bf[n][kk], acc[m][n], 0, 0, 0);

    __syncthreads();   // all waves done reading before next stage overwrites
  }

  // Epilogue: row m=(b,i), col n=(yo,v) -> out[b][yo][off + v*d + i]
  int yo4[4], v4[4];
#pragma unroll
  for (int n = 0; n < 4; ++n) {
    const int col = n0 + wc * 64 + n * 16 + r15;
    yo4[n] = col / d;
    v4[n] = col - yo4[n] * d;
  }
#pragma unroll
  for (int m = 0; m < 4; ++m)
#pragma unroll
    for (int j = 0; j < 4; ++j) {
      const int row = m0 + wr * 64 + m * 16 + khi * 4 + j;
      const int bb = row / d, i = row - bb * d;
      float* orow = out + (size_t)bb * 36608 + off + i;
#pragma unroll
      for (int n = 0; n < 4; ++n)
        orow[yo4[n] * 286 + v4[n] * d] = acc[m][n][j];
    }
}

// ---------------------------------------------------------------------------
extern "C" void kernel_launch(void* const* d_in, const int* in_sizes, int n_in,
                              void* d_out, int out_size, void* d_ws, size_t ws_size,
                              hipStream_t stream) {
  const float* x  = (const float*)d_in[0];  // (512,128,286)
  const float* w  = (const float*)d_in[1];  // (128,128,512)
  const float* Dm = (const float*)d_in[2];  // (512,286)
  float* out = (float*)d_out;               // (512,128,286)

  // Workspace (bf16 elems): PT = 16384*286 ; A = 65536*286
  __hip_bfloat16* PT = (__hip_bfloat16*)d_ws;
  __hip_bfloat16* A  = PT + 16384 * 286;

  psi_gemm<<<dim3(256, 5), dim3(NT), 0, stream>>>(w, Dm, PT);
  build_A<<<dim3(73216), dim3(NT), 0, stream>>>(x, A);
  main_gemm<<<dim3(1144), dim3(NT), 0, stream>>>(A, PT, out);
}

// Round 7
// 241.501 us; speedup vs baseline: 3.1336x; 1.2246x over previous
//
#include <hip/hip_runtime.h>
#include <hip/hip_bf16.h>

// SO3Conv restructured:
//   PT_l[(yo,v)][(x,u)] = psi_l scaled, bf16   (psi = D.w/sqrt(512))
//   A_l[(b,i)][(x,u)]   = permuted x, bf16
//   Y_l[(b,i)][(yo,v)]  = A_l . PT_l^T  via mfma_f32_16x16x32_bf16
// l=0..5, d=2l+1, off_l = {0,1,10,35,84,165}.
// PT_l base = 16384*off_l elems; A_l base = 65536*off_l elems.

#define NT 256
typedef __bf16 bf16x8 __attribute__((ext_vector_type(8)));
typedef float f32x4 __attribute__((ext_vector_type(4)));
typedef unsigned int u32;

__device__ __forceinline__ void gload_lds16(const void* g, void* l) {
  __builtin_amdgcn_global_load_lds(
      (const __attribute__((address_space(1))) u32*)g,
      (__attribute__((address_space(3))) u32*)l, 16, 0, 0);
}

__device__ __forceinline__ void decode_s(int s, int& off, int& d) {
  if (s >= 165)      { off = 165; d = 11; }
  else if (s >= 84)  { off = 84;  d = 9; }
  else if (s >= 35)  { off = 35;  d = 7; }
  else if (s >= 10)  { off = 10;  d = 5; }
  else if (s >= 1)   { off = 1;   d = 3; }
  else               { off = 0;   d = 1; }
}

// ---------------------------------------------------------------------------
// Kernel 0: prep.  blocks [0,4096): wb = bf16(w), 8 elems/thread.
//           blocks [4096,4864): DT[s][g] = bf16(D[g][s]), s>=286 -> 0.
// ---------------------------------------------------------------------------
__global__ __launch_bounds__(NT)
void prep(const float* __restrict__ w, const float* __restrict__ Dm,
          __hip_bfloat16* __restrict__ wb, __hip_bfloat16* __restrict__ DT) {
  const int bx = blockIdx.x;
  if (bx < 4096) {
    const int t = bx * NT + threadIdx.x;       // 1,048,576 threads x 8 elems
    const float4 a = reinterpret_cast<const float4*>(w)[t * 2];
    const float4 b = reinterpret_cast<const float4*>(w)[t * 2 + 1];
    __hip_bfloat16 v[8];
    v[0] = __float2bfloat16(a.x); v[1] = __float2bfloat16(a.y);
    v[2] = __float2bfloat16(a.z); v[3] = __float2bfloat16(a.w);
    v[4] = __float2bfloat16(b.x); v[5] = __float2bfloat16(b.y);
    v[6] = __float2bfloat16(b.z); v[7] = __float2bfloat16(b.w);
    *reinterpret_cast<bf16x8*>(&wb[t * 8]) = *reinterpret_cast<bf16x8*>(v);
  } else {
    const int e = (bx - 4096) * NT + threadIdx.x;  // 196,608 = 384*512
    const int s = e >> 9, g = e & 511;
    DT[e] = (s < 286) ? __float2bfloat16(Dm[g * 286 + s]) : __float2bfloat16(0.0f);
  }
}

// ---------------------------------------------------------------------------
// Kernel 1: psi MFMA GEMM.  C[m][s] = sum_g wb[m][g] * DT[s][g], K=512.
// m=(x*128+y).  Epilogue: PT_l[(y*d+v)*128d + x*d+u] = bf16(C/(256*sqrt(d))).
// Grid (128,3): 128x128 tiles over M=16384, N=384(padded).
// ---------------------------------------------------------------------------
__global__ __launch_bounds__(NT)
void psi_mfma(const __hip_bfloat16* __restrict__ wb,
              const __hip_bfloat16* __restrict__ DT,
              __hip_bfloat16* __restrict__ PT) {
  const int m0 = blockIdx.x * 128, n0 = blockIdx.y * 128;

  __shared__ __hip_bfloat16 sA[128 * 64];
  __shared__ __hip_bfloat16 sB[128 * 64];

  const int tid = threadIdx.x;
  const int lane = tid & 63, wave = tid >> 6;
  const int wr = wave & 1, wc = wave >> 1;
  const int r15 = lane & 15, khi = lane >> 4;

  f32x4 acc[4][4] = {};

  for (int kt = 0; kt < 512; kt += 64) {
#pragma unroll
    for (int c = 0; c < 4; ++c) {
      const int q = c * 256 + tid;
      const int row = q >> 3, slot = q & 7;
      const int scol = ((slot ^ (row & 7)) << 3);
      gload_lds16(&wb[(m0 + row) * 512 + kt + scol],
                  &sA[(c * 256 + wave * 64) << 3]);
      gload_lds16(&DT[(n0 + row) * 512 + kt + scol],
                  &sB[(c * 256 + wave * 64) << 3]);
    }
    __syncthreads();

    bf16x8 af[4][2], bf[4][2];
#pragma unroll
    for (int m = 0; m < 4; ++m)
#pragma unroll
      for (int kk = 0; kk < 2; ++kk) {
        const int row = wr * 64 + m * 16 + r15;
        const int slot = (kk * 4 + khi) ^ (row & 7);
        af[m][kk] = *reinterpret_cast<const bf16x8*>(&sA[row * 64 + slot * 8]);
      }
#pragma unroll
    for (int n = 0; n < 4; ++n)
#pragma unroll
      for (int kk = 0; kk < 2; ++kk) {
        const int row = wc * 64 + n * 16 + r15;
        const int slot = (kk * 4 + khi) ^ (row & 7);
        bf[n][kk] = *reinterpret_cast<const bf16x8*>(&sB[row * 64 + slot * 8]);
      }
#pragma unroll
    for (int kk = 0; kk < 2; ++kk)
#pragma unroll
      for (int m = 0; m < 4; ++m)
#pragma unroll
        for (int n = 0; n < 4; ++n)
          acc[m][n] = __builtin_amdgcn_mfma_f32_16x16x32_bf16(
              af[m][kk], bf[n][kk], acc[m][n], 0, 0, 0);

    __syncthreads();
  }

  // Scatter epilogue: col s -> (off,d,u,v); row m=(x,y).
#pragma unroll
  for (int n = 0; n < 4; ++n) {
    const int s = n0 + wc * 64 + n * 16 + r15;
    if (s >= 286) continue;
    int off, d;
    decode_s(s, off, d);
    const int rel = s - off;
    const int u = rel / d, v = rel - u * d;
    const float scale = 1.0f / (256.0f * sqrtf((float)d));
    __hip_bfloat16* Pl = PT + off * 16384;
    const int Kd = 128 * d;
#pragma unroll
    for (int m = 0; m < 4; ++m)
#pragma unroll
      for (int j = 0; j < 4; ++j) {
        const int row = m0 + wr * 64 + m * 16 + khi * 4 + j;
        const int x = row >> 7, y = row & 127;
        Pl[(y * d + v) * Kd + (x * d + u)] = __float2bfloat16(acc[m][n][j] * scale);
      }
  }
}

// ---------------------------------------------------------------------------
// Kernel 2: A_l[(b*d+i)*(128d) + x*d+u] = bf16( X[(b*128+x)*286 + off+u*d+i] )
// ---------------------------------------------------------------------------
__global__ __launch_bounds__(NT)
void build_A(const float* __restrict__ X, __hip_bfloat16* __restrict__ A) {
  const int idx = blockIdx.x * NT + threadIdx.x;
  int off, d;
  if (idx >= 65536 * 165)      { off = 165; d = 11; }
  else if (idx >= 65536 * 84)  { off = 84;  d = 9; }
  else if (idx >= 65536 * 35)  { off = 35;  d = 7; }
  else if (idx >= 65536 * 10)  { off = 10;  d = 5; }
  else if (idx >= 65536 * 1)   { off = 1;   d = 3; }
  else                         { off = 0;   d = 1; }
  const int rel = idx - 65536 * off;
  const int K = 128 * d;
  const int m = rel / K;
  const int k = rel - m * K;
  const int b = m / d, i = m - b * d;
  const int x = k / d, u = k - x * d;
  A[idx] = __float2bfloat16(X[(b * 128 + x) * 286 + off + u * d + i]);
}

// ---------------------------------------------------------------------------
// Kernel 3: MFMA main GEMM (unchanged from R2). 1144 blocks.
// ---------------------------------------------------------------------------
__global__ __launch_bounds__(NT)
void main_gemm(const __hip_bfloat16* __restrict__ Aall,
               const __hip_bfloat16* __restrict__ PTall,
               float* __restrict__ out) {
  int bx = blockIdx.x;
  int off, d;
  if (bx >= 660)      { off = 165; d = 11; bx -= 660; }
  else if (bx >= 336) { off = 84;  d = 9;  bx -= 336; }
  else if (bx >= 140) { off = 35;  d = 7;  bx -= 140; }
  else if (bx >= 40)  { off = 10;  d = 5;  bx -= 40; }
  else if (bx >= 4)   { off = 1;   d = 3;  bx -= 4; }
  else                { off = 0;   d = 1; }
  const int bm = bx % (4 * d);
  const int bn = bx / (4 * d);
  const int Kn = 128 * d;
  const __hip_bfloat16* A  = Aall  + 65536 * off;
  const __hip_bfloat16* BT = PTall + 16384 * off;
  const int m0 = bm * 128, n0 = bn * 128;

  __shared__ __hip_bfloat16 sA[128 * 64];
  __shared__ __hip_bfloat16 sB[128 * 64];

  const int tid = threadIdx.x;
  const int lane = tid & 63, wave = tid >> 6;
  const int wr = wave & 1, wc = wave >> 1;
  const int r15 = lane & 15, khi = lane >> 4;

  f32x4 acc[4][4] = {};

  for (int kt = 0; kt < Kn; kt += 64) {
#pragma unroll
    for (int c = 0; c < 4; ++c) {
      const int q = c * 256 + tid;
      const int row = q >> 3, slot = q & 7;
      const int scol = ((slot ^ (row & 7)) << 3);
      gload_lds16(&A[(m0 + row) * Kn + kt + scol],
                  &sA[(c * 256 + wave * 64) << 3]);
      gload_lds16(&BT[(n0 + row) * Kn + kt + scol],
                  &sB[(c * 256 + wave * 64) << 3]);
    }
    __syncthreads();

    bf16x8 af[4][2], bf[4][2];
#pragma unroll
    for (int m = 0; m < 4; ++m)
#pragma unroll
      for (int kk = 0; kk < 2; ++kk) {
        const int row = wr * 64 + m * 16 + r15;
        const int slot = (kk * 4 + khi) ^ (row & 7);
        af[m][kk] = *reinterpret_cast<const bf16x8*>(&sA[row * 64 + slot * 8]);
      }
#pragma unroll
    for (int n = 0; n < 4; ++n)
#pragma unroll
      for (int kk = 0; kk < 2; ++kk) {
        const int row = wc * 64 + n * 16 + r15;
        const int slot = (kk * 4 + khi) ^ (row & 7);
        bf[n][kk] = *reinterpret_cast<const bf16x8*>(&sB[row * 64 + slot * 8]);
      }
#pragma unroll
    for (int kk = 0; kk < 2; ++kk)
#pragma unroll
      for (int m = 0; m < 4; ++m)
#pragma unroll
        for (int n = 0; n < 4; ++n)
          acc[m][n] = __builtin_amdgcn_mfma_f32_16x16x32_bf16(
              af[m][kk], bf[n][kk], acc[m][n], 0, 0, 0);

    __syncthreads();
  }

  int yo4[4], v4[4];
#pragma unroll
  for (int n = 0; n < 4; ++n) {
    const int col = n0 + wc * 64 + n * 16 + r15;
    yo4[n] = col / d;
    v4[n] = col - yo4[n] * d;
  }
#pragma unroll
  for (int m = 0; m < 4; ++m)
#pragma unroll
    for (int j = 0; j < 4; ++j) {
      const int row = m0 + wr * 64 + m * 16 + khi * 4 + j;
      const int bb = row / d, i = row - bb * d;
      float* orow = out + (size_t)bb * 36608 + off + i;
#pragma unroll
      for (int n = 0; n < 4; ++n)
        orow[yo4[n] * 286 + v4[n] * d] = acc[m][n][j];
    }
}

// ---------------------------------------------------------------------------
extern "C" void kernel_launch(void* const* d_in, const int* in_sizes, int n_in,
                              void* d_out, int out_size, void* d_ws, size_t ws_size,
                              hipStream_t stream) {
  const float* x  = (const float*)d_in[0];  // (512,128,286)
  const float* w  = (const float*)d_in[1];  // (128,128,512)
  const float* Dm = (const float*)d_in[2];  // (512,286)
  float* out = (float*)d_out;               // (512,128,286)

  // Workspace (bf16 elems):
  //   PT: 16384*286 = 4,687,872
  //   A:  65536*286 = 18,743,296
  //   wb: 16384*512 = 8,388,608
  //   DT:   384*512 =   196,608      total ~64 MB
  __hip_bfloat16* PT = (__hip_bfloat16*)d_ws;
  __hip_bfloat16* A  = PT + 16384 * 286;
  __hip_bfloat16* wb = A + 65536 * 286;
  __hip_bfloat16* DT = wb + 16384 * 512;

  prep<<<dim3(4864), dim3(NT), 0, stream>>>(w, Dm, wb, DT);
  psi_mfma<<<dim3(128, 3), dim3(NT), 0, stream>>>(wb, DT, PT);
  build_A<<<dim3(73216), dim3(NT), 0, stream>>>(x, A);
  main_gemm<<<dim3(1144), dim3(NT), 0, stream>>>(A, PT, out);
}

// Round 8
// 178.971 us; speedup vs baseline: 4.2285x; 1.3494x over previous
//
#include <hip/hip_runtime.h>
#include <hip/hip_bf16.h>

// SO3Conv restructured:
//   PT_l[(yo,v)][(x,u)] = psi_l scaled, bf16   (psi = D.w/sqrt(512))
//   A_l[(b,i)][(x,u)]   = permuted x, bf16
//   Y_l[(b,i)][(yo,v)]  = A_l . PT_l^T  via mfma_f32_16x16x32_bf16
// l=0..5, d=2l+1, off_l = {0,1,10,35,84,165}.
// PT_l base = 16384*off_l elems; A_l base = 65536*off_l elems.

#define NT 256
typedef __bf16 bf16x8 __attribute__((ext_vector_type(8)));
typedef float f32x4 __attribute__((ext_vector_type(4)));
typedef unsigned int u32;

__device__ __forceinline__ void gload_lds16(const void* g, void* l) {
  __builtin_amdgcn_global_load_lds(
      (const __attribute__((address_space(1))) u32*)g,
      (__attribute__((address_space(3))) u32*)l, 16, 0, 0);
}

__device__ __forceinline__ void decode_s(int s, int& off, int& d) {
  if (s >= 165)      { off = 165; d = 11; }
  else if (s >= 84)  { off = 84;  d = 9; }
  else if (s >= 35)  { off = 35;  d = 7; }
  else if (s >= 10)  { off = 10;  d = 5; }
  else if (s >= 1)   { off = 1;   d = 3; }
  else               { off = 0;   d = 1; }
}

// ---------------------------------------------------------------------------
// Kernel 0: prep.  blocks [0,4096): wb = bf16(w), 8 elems/thread.
//           blocks [4096,4864): DT[s][g] = bf16(D[g][s]), s>=286 -> 0.
// ---------------------------------------------------------------------------
__global__ __launch_bounds__(NT)
void prep(const float* __restrict__ w, const float* __restrict__ Dm,
          __hip_bfloat16* __restrict__ wb, __hip_bfloat16* __restrict__ DT) {
  const int bx = blockIdx.x;
  if (bx < 4096) {
    const int t = bx * NT + threadIdx.x;
    const float4 a = reinterpret_cast<const float4*>(w)[t * 2];
    const float4 b = reinterpret_cast<const float4*>(w)[t * 2 + 1];
    __hip_bfloat16 v[8];
    v[0] = __float2bfloat16(a.x); v[1] = __float2bfloat16(a.y);
    v[2] = __float2bfloat16(a.z); v[3] = __float2bfloat16(a.w);
    v[4] = __float2bfloat16(b.x); v[5] = __float2bfloat16(b.y);
    v[6] = __float2bfloat16(b.z); v[7] = __float2bfloat16(b.w);
    *reinterpret_cast<bf16x8*>(&wb[t * 8]) = *reinterpret_cast<bf16x8*>(v);
  } else {
    const int e = (bx - 4096) * NT + threadIdx.x;  // 196,608 = 384*512
    const int s = e >> 9, g = e & 511;
    DT[e] = (s < 286) ? __float2bfloat16(Dm[g * 286 + s]) : __float2bfloat16(0.0f);
  }
}

// Staging macro shared by both MFMA kernels (linear LDS dest, pre-swizzled src)
#define STAGE(buf, Aptr, Bptr, LDK, ktv)                                     \
  {                                                                          \
    _Pragma("unroll")                                                        \
    for (int c = 0; c < 4; ++c) {                                            \
      const int q = c * 256 + tid;                                           \
      const int row = q >> 3, slot = q & 7;                                  \
      const int scol = ((slot ^ (row & 7)) << 3);                            \
      gload_lds16(&Aptr[(m0 + row) * (LDK) + (ktv) + scol],                  \
                  &sA[buf][(c * 256 + wave * 64) << 3]);                     \
      gload_lds16(&Bptr[(n0 + row) * (LDK) + (ktv) + scol],                  \
                  &sB[buf][(c * 256 + wave * 64) << 3]);                     \
    }                                                                        \
  }

#define LOAD_FRAGS(buf)                                                      \
  {                                                                          \
    _Pragma("unroll")                                                        \
    for (int m = 0; m < 4; ++m)                                              \
      _Pragma("unroll")                                                      \
      for (int kk = 0; kk < 2; ++kk) {                                       \
        const int row = wr * 64 + m * 16 + r15;                              \
        const int slot = (kk * 4 + khi) ^ (row & 7);                         \
        af[m][kk] = *reinterpret_cast<const bf16x8*>(&sA[buf][row * 64 + slot * 8]); \
      }                                                                      \
    _Pragma("unroll")                                                        \
    for (int n = 0; n < 4; ++n)                                              \
      _Pragma("unroll")                                                      \
      for (int kk = 0; kk < 2; ++kk) {                                       \
        const int row = wc * 64 + n * 16 + r15;                              \
        const int slot = (kk * 4 + khi) ^ (row & 7);                         \
        bf[n][kk] = *reinterpret_cast<const bf16x8*>(&sB[buf][row * 64 + slot * 8]); \
      }                                                                      \
  }

#define DO_MFMA()                                                            \
  {                                                                          \
    _Pragma("unroll")                                                        \
    for (int kk = 0; kk < 2; ++kk)                                           \
      _Pragma("unroll")                                                      \
      for (int m = 0; m < 4; ++m)                                            \
        _Pragma("unroll")                                                    \
        for (int n = 0; n < 4; ++n)                                          \
          acc[m][n] = __builtin_amdgcn_mfma_f32_16x16x32_bf16(               \
              af[m][kk], bf[n][kk], acc[m][n], 0, 0, 0);                     \
  }

// ---------------------------------------------------------------------------
// Kernel 1: psi MFMA GEMM, double-buffered.  C[m][s] = sum_g wb[m][g]*DT[s][g]
// K=512 (8 tiles).  Epilogue: PT_l[(y*d+v)*128d + x*d+u] = bf16(C*scale).
// Grid (128,3).
// ---------------------------------------------------------------------------
__global__ __launch_bounds__(NT)
void psi_mfma(const __hip_bfloat16* __restrict__ wb,
              const __hip_bfloat16* __restrict__ DT,
              __hip_bfloat16* __restrict__ PT) {
  const int m0 = blockIdx.x * 128, n0 = blockIdx.y * 128;

  __shared__ __hip_bfloat16 sA[2][128 * 64];
  __shared__ __hip_bfloat16 sB[2][128 * 64];

  const int tid = threadIdx.x;
  const int lane = tid & 63, wave = tid >> 6;
  const int wr = wave & 1, wc = wave >> 1;
  const int r15 = lane & 15, khi = lane >> 4;

  f32x4 acc[4][4] = {};
  bf16x8 af[4][2], bf[4][2];

  STAGE(0, wb, DT, 512, 0);
  __syncthreads();
  int cur = 0;
  for (int t = 0; t < 8; ++t) {
    if (t + 1 < 8) STAGE(cur ^ 1, wb, DT, 512, (t + 1) << 6);
    LOAD_FRAGS(cur);
    DO_MFMA();
    if (t + 1 < 8) { __syncthreads(); cur ^= 1; }
  }

  // Scatter epilogue: col s -> (off,d,u,v); row m=(x,y).
#pragma unroll
  for (int n = 0; n < 4; ++n) {
    const int s = n0 + wc * 64 + n * 16 + r15;
    if (s >= 286) continue;
    int off, d;
    decode_s(s, off, d);
    const int rel = s - off;
    const int u = rel / d, v = rel - u * d;
    const float scale = 1.0f / (256.0f * sqrtf((float)d));
    __hip_bfloat16* Pl = PT + off * 16384;
    const int Kd = 128 * d;
#pragma unroll
    for (int m = 0; m < 4; ++m)
#pragma unroll
      for (int j = 0; j < 4; ++j) {
        const int row = m0 + wr * 64 + m * 16 + khi * 4 + j;
        const int x = row >> 7, y = row & 127;
        Pl[(y * d + v) * Kd + (x * d + u)] = __float2bfloat16(acc[m][n][j] * scale);
      }
  }
}

// ---------------------------------------------------------------------------
// Kernel 2: build_A, per-degree LDS transpose. One block per b (512 blocks),
// compile-time D,OFF -> divisions become magic-mul; both sides coalesced.
//   read  X[b][x][OFF + u*D + i]  (contiguous D*D per x)
//   write A_l[(b*D+i)*(128D) + x*D+u]  (contiguous rows)
// ---------------------------------------------------------------------------
template<int D, int OFF>
__global__ __launch_bounds__(NT)
void build_A_t(const float* __restrict__ X, __hip_bfloat16* __restrict__ A) {
  const int b = blockIdx.x;
  __shared__ __hip_bfloat16 sm[128 * D * D];   // <= 31 KB at D=11
  const float* src = X + (size_t)b * (128 * 286) + OFF;
  for (int e = threadIdx.x; e < 128 * D * D; e += NT) {
    const int x = e / (D * D), r = e - x * (D * D);
    sm[e] = __float2bfloat16(src[x * 286 + r]);
  }
  __syncthreads();
  __hip_bfloat16* dst = A + (size_t)65536 * OFF + (size_t)b * (D * 128 * D);
  for (int o = threadIdx.x; o < D * 128 * D; o += NT) {
    const int i = o / (128 * D);
    const int rem = o - i * (128 * D);
    const int x = rem / D, u = rem - x * D;
    dst[o] = sm[x * D * D + u * D + i];
  }
}

// ---------------------------------------------------------------------------
// Kernel 3: MFMA main GEMM, double-buffered. 1144 blocks, longest degree
// first (l=5 K=1408 at bx 0) to shrink the tail.
// ---------------------------------------------------------------------------
__global__ __launch_bounds__(NT)
void main_gemm(const __hip_bfloat16* __restrict__ Aall,
               const __hip_bfloat16* __restrict__ PTall,
               float* __restrict__ out) {
  int bx = blockIdx.x;
  int off, d;
  if (bx < 484)       { off = 165; d = 11; }
  else if (bx < 808)  { off = 84;  d = 9;  bx -= 484; }
  else if (bx < 1004) { off = 35;  d = 7;  bx -= 808; }
  else if (bx < 1104) { off = 10;  d = 5;  bx -= 1004; }
  else if (bx < 1140) { off = 1;   d = 3;  bx -= 1104; }
  else                { off = 0;   d = 1;  bx -= 1140; }
  const int bm = bx % (4 * d);
  const int bn = bx / (4 * d);
  const int Kn = 128 * d;
  const __hip_bfloat16* A  = Aall  + 65536 * off;
  const __hip_bfloat16* BT = PTall + 16384 * off;
  const int m0 = bm * 128, n0 = bn * 128;

  __shared__ __hip_bfloat16 sA[2][128 * 64];
  __shared__ __hip_bfloat16 sB[2][128 * 64];

  const int tid = threadIdx.x;
  const int lane = tid & 63, wave = tid >> 6;
  const int wr = wave & 1, wc = wave >> 1;
  const int r15 = lane & 15, khi = lane >> 4;

  f32x4 acc[4][4] = {};
  bf16x8 af[4][2], bf[4][2];

  const int nk = Kn >> 6;
  STAGE(0, A, BT, Kn, 0);
  __syncthreads();
  int cur = 0;
  for (int t = 0; t < nk; ++t) {
    if (t + 1 < nk) STAGE(cur ^ 1, A, BT, Kn, (t + 1) << 6);
    LOAD_FRAGS(cur);
    DO_MFMA();
    if (t + 1 < nk) { __syncthreads(); cur ^= 1; }
  }

  // Epilogue: row m=(b,i), col n=(yo,v) -> out[b][yo][off + v*d + i]
  int yo4[4], v4[4];
#pragma unroll
  for (int n = 0; n < 4; ++n) {
    const int col = n0 + wc * 64 + n * 16 + r15;
    yo4[n] = col / d;
    v4[n] = col - yo4[n] * d;
  }
#pragma unroll
  for (int m = 0; m < 4; ++m)
#pragma unroll
    for (int j = 0; j < 4; ++j) {
      const int row = m0 + wr * 64 + m * 16 + khi * 4 + j;
      const int bb = row / d, i = row - bb * d;
      float* orow = out + (size_t)bb * 36608 + off + i;
#pragma unroll
      for (int n = 0; n < 4; ++n)
        orow[yo4[n] * 286 + v4[n] * d] = acc[m][n][j];
    }
}

// ---------------------------------------------------------------------------
extern "C" void kernel_launch(void* const* d_in, const int* in_sizes, int n_in,
                              void* d_out, int out_size, void* d_ws, size_t ws_size,
                              hipStream_t stream) {
  const float* x  = (const float*)d_in[0];  // (512,128,286)
  const float* w  = (const float*)d_in[1];  // (128,128,512)
  const float* Dm = (const float*)d_in[2];  // (512,286)
  float* out = (float*)d_out;               // (512,128,286)

  // Workspace (bf16 elems):
  //   PT: 16384*286 ; A: 65536*286 ; wb: 16384*512 ; DT: 384*512
  __hip_bfloat16* PT = (__hip_bfloat16*)d_ws;
  __hip_bfloat16* A  = PT + 16384 * 286;
  __hip_bfloat16* wb = A + 65536 * 286;
  __hip_bfloat16* DT = wb + 16384 * 512;

  prep<<<dim3(4864), dim3(NT), 0, stream>>>(w, Dm, wb, DT);
  psi_mfma<<<dim3(128, 3), dim3(NT), 0, stream>>>(wb, DT, PT);
  build_A_t<1, 0><<<dim3(512), dim3(NT), 0, stream>>>(x, A);
  build_A_t<3, 1><<<dim3(512), dim3(NT), 0, stream>>>(x, A);
  build_A_t<5, 10><<<dim3(512), dim3(NT), 0, stream>>>(x, A);
  build_A_t<7, 35><<<dim3(512), dim3(NT), 0, stream>>>(x, A);
  build_A_t<9, 84><<<dim3(512), dim3(NT), 0, stream>>>(x, A);
  build_A_t<11, 165><<<dim3(512), dim3(NT), 0, stream>>>(x, A);
  main_gemm<<<dim3(1144), dim3(NT), 0, stream>>>(A, PT, out);
}

// Round 9
// 167.350 us; speedup vs baseline: 4.5221x; 1.0694x over previous
//
#include <hip/hip_runtime.h>
#include <hip/hip_bf16.h>

// SO3Conv restructured:
//   PT_l[(yo,v)][(x,u)] = psi_l scaled, bf16   (psi = D.w/sqrt(512))
//   A_l[(b,i)][(x,u)]   = permuted x, bf16
//   Y_l[(b,i)][(yo,v)]  = A_l . PT_l^T  via mfma_f32_16x16x32_bf16
// l=0..5, d=2l+1, off_l = {0,1,10,35,84,165}.
// PT_l base = 16384*off_l elems; A_l base = 65536*off_l elems.

#define NT 256
#define NTILES 1144
#define NWORKERS 768
typedef __bf16 bf16x8 __attribute__((ext_vector_type(8)));
typedef float f32x4 __attribute__((ext_vector_type(4)));
typedef unsigned int u32;

__device__ __forceinline__ void gload_lds16(const void* g, void* l) {
  __builtin_amdgcn_global_load_lds(
      (const __attribute__((address_space(1))) u32*)g,
      (__attribute__((address_space(3))) u32*)l, 16, 0, 0);
}

__device__ __forceinline__ void decode_s(int s, int& off, int& d) {
  if (s >= 165)      { off = 165; d = 11; }
  else if (s >= 84)  { off = 84;  d = 9; }
  else if (s >= 35)  { off = 35;  d = 7; }
  else if (s >= 10)  { off = 10;  d = 5; }
  else if (s >= 1)   { off = 1;   d = 3; }
  else               { off = 0;   d = 1; }
}

// ---------------------------------------------------------------------------
// Shared GEMM helpers (proven structure from R7/R8; LDS 16B-slot XOR swizzle,
// linear LDS dest for global_load_lds, pre-swizzled global source).
// ---------------------------------------------------------------------------
__device__ __forceinline__ void stage_tile(
    const __hip_bfloat16* __restrict__ Ap, const __hip_bfloat16* __restrict__ Bp,
    int LDK, int ktv, int m0, int n0, int tid, int wave,
    __hip_bfloat16* sA, __hip_bfloat16* sB) {
#pragma unroll
  for (int c = 0; c < 4; ++c) {
    const int q = c * 256 + tid;
    const int row = q >> 3, slot = q & 7;
    const int scol = ((slot ^ (row & 7)) << 3);
    gload_lds16(&Ap[(m0 + row) * LDK + ktv + scol], &sA[(c * 256 + wave * 64) << 3]);
    gload_lds16(&Bp[(n0 + row) * LDK + ktv + scol], &sB[(c * 256 + wave * 64) << 3]);
  }
}

__device__ __forceinline__ void load_frags(
    const __hip_bfloat16* sA, const __hip_bfloat16* sB,
    int wr, int wc, int r15, int khi, bf16x8 (&af)[4][2], bf16x8 (&bf)[4][2]) {
#pragma unroll
  for (int m = 0; m < 4; ++m)
#pragma unroll
    for (int kk = 0; kk < 2; ++kk) {
      const int row = wr * 64 + m * 16 + r15;
      const int slot = (kk * 4 + khi) ^ (row & 7);
      af[m][kk] = *reinterpret_cast<const bf16x8*>(&sA[row * 64 + slot * 8]);
    }
#pragma unroll
  for (int n = 0; n < 4; ++n)
#pragma unroll
    for (int kk = 0; kk < 2; ++kk) {
      const int row = wc * 64 + n * 16 + r15;
      const int slot = (kk * 4 + khi) ^ (row & 7);
      bf[n][kk] = *reinterpret_cast<const bf16x8*>(&sB[row * 64 + slot * 8]);
    }
}

__device__ __forceinline__ void do_mfma(
    const bf16x8 (&af)[4][2], const bf16x8 (&bf)[4][2], f32x4 (&acc)[4][4]) {
#pragma unroll
  for (int kk = 0; kk < 2; ++kk)
#pragma unroll
    for (int m = 0; m < 4; ++m)
#pragma unroll
      for (int n = 0; n < 4; ++n)
        acc[m][n] = __builtin_amdgcn_mfma_f32_16x16x32_bf16(
            af[m][kk], bf[n][kk], acc[m][n], 0, 0, 0);
}

// ---------------------------------------------------------------------------
// Kernel 0: prep.  blocks [0,4096): wb = bf16(w); [4096,4864): DT = bf16(D^T)
// padded to 384 rows.  Also zeroes the work-queue counter (bx 0, tid 0).
// ---------------------------------------------------------------------------
__global__ __launch_bounds__(NT)
void prep(const float* __restrict__ w, const float* __restrict__ Dm,
          __hip_bfloat16* __restrict__ wb, __hip_bfloat16* __restrict__ DT,
          int* __restrict__ cnt) {
  const int bx = blockIdx.x;
  if (bx == 0 && threadIdx.x == 0) *cnt = 0;
  if (bx < 4096) {
    const int t = bx * NT + threadIdx.x;
    const float4 a = reinterpret_cast<const float4*>(w)[t * 2];
    const float4 b = reinterpret_cast<const float4*>(w)[t * 2 + 1];
    __hip_bfloat16 v[8];
    v[0] = __float2bfloat16(a.x); v[1] = __float2bfloat16(a.y);
    v[2] = __float2bfloat16(a.z); v[3] = __float2bfloat16(a.w);
    v[4] = __float2bfloat16(b.x); v[5] = __float2bfloat16(b.y);
    v[6] = __float2bfloat16(b.z); v[7] = __float2bfloat16(b.w);
    *reinterpret_cast<bf16x8*>(&wb[t * 8]) = *reinterpret_cast<bf16x8*>(v);
  } else {
    const int e = (bx - 4096) * NT + threadIdx.x;  // 196,608 = 384*512
    const int s = e >> 9, g = e & 511;
    DT[e] = (s < 286) ? __float2bfloat16(Dm[g * 286 + s]) : __float2bfloat16(0.0f);
  }
}

// ---------------------------------------------------------------------------
// Kernel 1: psi MFMA GEMM (double-buffered, unchanged from R8).
// C[m][s] = sum_g wb[m][g]*DT[s][g], K=512. Grid (128,3).
// ---------------------------------------------------------------------------
__global__ __launch_bounds__(NT)
void psi_mfma(const __hip_bfloat16* __restrict__ wb,
              const __hip_bfloat16* __restrict__ DT,
              __hip_bfloat16* __restrict__ PT) {
  const int m0 = blockIdx.x * 128, n0 = blockIdx.y * 128;

  __shared__ __hip_bfloat16 sA[2][128 * 64];
  __shared__ __hip_bfloat16 sB[2][128 * 64];

  const int tid = threadIdx.x;
  const int lane = tid & 63, wave = tid >> 6;
  const int wr = wave & 1, wc = wave >> 1;
  const int r15 = lane & 15, khi = lane >> 4;

  f32x4 acc[4][4] = {};
  bf16x8 af[4][2], bf[4][2];

  stage_tile(wb, DT, 512, 0, m0, n0, tid, wave, sA[0], sB[0]);
  __syncthreads();
  int cur = 0;
  for (int t = 0; t < 8; ++t) {
    if (t + 1 < 8)
      stage_tile(wb, DT, 512, (t + 1) << 6, m0, n0, tid, wave, sA[cur ^ 1], sB[cur ^ 1]);
    load_frags(sA[cur], sB[cur], wr, wc, r15, khi, af, bf);
    do_mfma(af, bf, acc);
    if (t + 1 < 8) { __syncthreads(); cur ^= 1; }
  }

  // Scatter epilogue: col s -> (off,d,u,v); row m=(x,y).
#pragma unroll
  for (int n = 0; n < 4; ++n) {
    const int s = n0 + wc * 64 + n * 16 + r15;
    if (s >= 286) continue;
    int off, d;
    decode_s(s, off, d);
    const int rel = s - off;
    const int u = rel / d, v = rel - u * d;
    const float scale = 1.0f / (256.0f * sqrtf((float)d));
    __hip_bfloat16* Pl = PT + off * 16384;
    const int Kd = 128 * d;
#pragma unroll
    for (int m = 0; m < 4; ++m)
#pragma unroll
      for (int j = 0; j < 4; ++j) {
        const int row = m0 + wr * 64 + m * 16 + khi * 4 + j;
        const int x = row >> 7, y = row & 127;
        Pl[(y * d + v) * Kd + (x * d + u)] = __float2bfloat16(acc[m][n][j] * scale);
      }
  }
}

// ---------------------------------------------------------------------------
// Kernel 2: build_A, all degrees in ONE launch (3072 blocks, big-D first).
// Per (b,l): LDS transpose, compile-time D/OFF (no runtime divides).
//   read  X[b][x][OFF + u*D + i]  -> write A_l[(b*D+i)*(128D) + x*D+u]
// ---------------------------------------------------------------------------
template<int D, int OFF>
__device__ __forceinline__ void build_one(const float* __restrict__ X,
                                          __hip_bfloat16* __restrict__ A,
                                          int b, __hip_bfloat16* sm) {
  const float* src = X + (size_t)b * (128 * 286) + OFF;
  for (int e = threadIdx.x; e < 128 * D * D; e += NT) {
    const int x = e / (D * D), r = e - x * (D * D);
    sm[e] = __float2bfloat16(src[x * 286 + r]);
  }
  __syncthreads();
  __hip_bfloat16* dst = A + (size_t)65536 * OFF + (size_t)b * (D * 128 * D);
  for (int o = threadIdx.x; o < D * 128 * D; o += NT) {
    const int i = o / (128 * D);
    const int rem = o - i * (128 * D);
    const int x = rem / D, u = rem - x * D;
    dst[o] = sm[x * D * D + u * D + i];
  }
}

__global__ __launch_bounds__(NT)
void build_A_all(const float* __restrict__ X, __hip_bfloat16* __restrict__ A) {
  __shared__ __hip_bfloat16 sm[128 * 121];
  const int bx = blockIdx.x;
  if (bx < 512)       build_one<11, 165>(X, A, bx, sm);
  else if (bx < 1024) build_one<9, 84>(X, A, bx - 512, sm);
  else if (bx < 1536) build_one<7, 35>(X, A, bx - 1024, sm);
  else if (bx < 2048) build_one<5, 10>(X, A, bx - 1536, sm);
  else if (bx < 2560) build_one<3, 1>(X, A, bx - 2048, sm);
  else                build_one<1, 0>(X, A, bx - 2560, sm);
}

// ---------------------------------------------------------------------------
// Kernel 3: persistent MFMA main GEMM. 768 worker blocks pull tile ids from a
// global atomic queue (longest-degree tiles first). Single 32 KiB LDS buffer
// (max residency); inner loop identical to R7's verified structure.
// ---------------------------------------------------------------------------
__global__ __launch_bounds__(NT)
void main_gemm(const __hip_bfloat16* __restrict__ Aall,
               const __hip_bfloat16* __restrict__ PTall,
               float* __restrict__ out, int* __restrict__ cnt) {
  __shared__ __hip_bfloat16 sA[128 * 64];
  __shared__ __hip_bfloat16 sB[128 * 64];
  __shared__ int s_tile;

  const int tid = threadIdx.x;
  const int lane = tid & 63, wave = tid >> 6;
  const int wr = wave & 1, wc = wave >> 1;
  const int r15 = lane & 15, khi = lane >> 4;

  for (;;) {
    if (tid == 0) s_tile = atomicAdd(cnt, 1);
    __syncthreads();               // broadcast tile id; also guards LDS reuse
    int bx = s_tile;
    if (bx >= NTILES) return;

    int off, d;
    if (bx < 484)       { off = 165; d = 11; }
    else if (bx < 808)  { off = 84;  d = 9;  bx -= 484; }
    else if (bx < 1004) { off = 35;  d = 7;  bx -= 808; }
    else if (bx < 1104) { off = 10;  d = 5;  bx -= 1004; }
    else if (bx < 1140) { off = 1;   d = 3;  bx -= 1104; }
    else                { off = 0;   d = 1;  bx -= 1140; }
    const int bm = bx % (4 * d);
    const int bn = bx / (4 * d);
    const int Kn = 128 * d;
    const __hip_bfloat16* A  = Aall  + 65536 * off;
    const __hip_bfloat16* BT = PTall + 16384 * off;
    const int m0 = bm * 128, n0 = bn * 128;

    f32x4 acc[4][4] = {};
    bf16x8 af[4][2], bf[4][2];

    const int nk = Kn >> 6;
    for (int t = 0; t < nk; ++t) {
      stage_tile(A, BT, Kn, t << 6, m0, n0, tid, wave, sA, sB);
      __syncthreads();
      load_frags(sA, sB, wr, wc, r15, khi, af, bf);
      do_mfma(af, bf, acc);
      if (t + 1 < nk) __syncthreads();
    }

    // Epilogue: row m=(b,i), col n=(yo,v) -> out[b][yo][off + v*d + i]
    int yo4[4], v4[4];
#pragma unroll
    for (int n = 0; n < 4; ++n) {
      const int col = n0 + wc * 64 + n * 16 + r15;
      yo4[n] = col / d;
      v4[n] = col - yo4[n] * d;
    }
#pragma unroll
    for (int m = 0; m < 4; ++m)
#pragma unroll
      for (int j = 0; j < 4; ++j) {
        const int row = m0 + wr * 64 + m * 16 + khi * 4 + j;
        const int bb = row / d, i = row - bb * d;
        float* orow = out + (size_t)bb * 36608 + off + i;
#pragma unroll
        for (int n = 0; n < 4; ++n)
          orow[yo4[n] * 286 + v4[n] * d] = acc[m][n][j];
      }
  }
}

// ---------------------------------------------------------------------------
extern "C" void kernel_launch(void* const* d_in, const int* in_sizes, int n_in,
                              void* d_out, int out_size, void* d_ws, size_t ws_size,
                              hipStream_t stream) {
  const float* x  = (const float*)d_in[0];  // (512,128,286)
  const float* w  = (const float*)d_in[1];  // (128,128,512)
  const float* Dm = (const float*)d_in[2];  // (512,286)
  float* out = (float*)d_out;               // (512,128,286)

  // Workspace (bf16 elems): PT 16384*286 ; A 65536*286 ; wb 16384*512 ;
  // DT 384*512 ; then a 4-byte work-queue counter (byte offset 64,032,768).
  __hip_bfloat16* PT = (__hip_bfloat16*)d_ws;
  __hip_bfloat16* A  = PT + 16384 * 286;
  __hip_bfloat16* wb = A + 65536 * 286;
  __hip_bfloat16* DT = wb + 16384 * 512;
  int* cnt = (int*)(DT + 384 * 512);

  prep<<<dim3(4864), dim3(NT), 0, stream>>>(w, Dm, wb, DT, cnt);
  psi_mfma<<<dim3(128, 3), dim3(NT), 0, stream>>>(wb, DT, PT);
  build_A_all<<<dim3(3072), dim3(NT), 0, stream>>>(x, A);
  main_gemm<<<dim3(NWORKERS), dim3(NT), 0, stream>>>(A, PT, out, cnt);
}